// Round 1
// baseline (5708.988 us; speedup 1.0000x reference)
//
#include <hip/hip_runtime.h>

#define NB 256
#define CIN 32
#define HWDIM 48
#define EDIM 256
#define KF 8
#define OW 41
#define LPOS 1681
#define EPSV 1e-5f

__device__ __forceinline__ float waveSum(float v){
#pragma unroll
  for(int o=32;o;o>>=1) v += __shfl_xor(v,o);
  return v;
}

// ---------------------------------------------------------------------------
// k_prep: gw[e] = ln1_g[e] * (sum_f bq[f]*wk[f,e]);
//         cst[0] = sum_e ln1_g[e]*wq_eff[e]; cst[1] = sum_e ln1_b[e]*wq_eff[e] + bq.bk
// ---------------------------------------------------------------------------
__global__ __launch_bounds__(256) void k_prep(const float* __restrict__ wk,
    const float* __restrict__ bq, const float* __restrict__ bk,
    const float* __restrict__ g1, const float* __restrict__ b1,
    float* __restrict__ gw, float* __restrict__ cst){
  int e = threadIdx.x;
  float acc = 0.f;
  for(int f=0; f<EDIM; f++) acc += bq[f]*wk[f*EDIM+e];
  float gwe = g1[e]*acc;
  gw[e] = gwe;
  float v0 = gwe;                       // -> sgw
  float v1 = b1[e]*acc + bq[e]*bk[e];   // -> sbw + c
  v0 = waveSum(v0); v1 = waveSum(v1);
  __shared__ float buf[2][4];
  if((e&63)==0){ buf[0][e>>6]=v0; buf[1][e>>6]=v1; }
  __syncthreads();
  if(e==0){
    cst[0]=buf[0][0]+buf[0][1]+buf[0][2]+buf[0][3];
    cst[1]=buf[1][0]+buf[1][1]+buf[1][2]+buf[1][3];
  }
}

// ---------------------------------------------------------------------------
// k_wt: wT[(c*8+ky)*8+kx][e] = conv_w[e][c][ky][kx]  (coalesced weight reads later)
// ---------------------------------------------------------------------------
__global__ __launch_bounds__(256) void k_wt(const float* __restrict__ w,
                                            float* __restrict__ wT){
  int j = blockIdx.x; int e = threadIdx.x;
  wT[(size_t)j*EDIM + e] = w[(size_t)e*2048 + j];
}

// ---------------------------------------------------------------------------
// k_conv: one block per (oy, b). thread = output channel e.
// Computes f[b,e,oy,0..40], then LN stats + score via cross-thread reduction.
// ---------------------------------------------------------------------------
__global__ __launch_bounds__(256) void k_conv(const float* __restrict__ xc,
    const float* __restrict__ xt, const float* __restrict__ wT,
    const float* __restrict__ cbias, const float* __restrict__ gw,
    const float* __restrict__ cst, float* __restrict__ scores){
  const int oy  = blockIdx.x;
  const int b   = blockIdx.y;
  const int tid = threadIdx.x;
  const float* __restrict__ xb = (b<128) ? (xc + (size_t)b*CIN*HWDIM*HWDIM)
                                         : (xt + (size_t)(b-128)*CIN*HWDIM*HWDIM);
  __shared__ float band[CIN*KF*HWDIM];   // 12288 floats = 48 KB: rows oy..oy+7, all 32 ch
  __shared__ float red[OW][12];
  for(int k=tid;k<CIN*KF*HWDIM;k+=256){
    int c = k/(KF*HWDIM); int rem = k - c*(KF*HWDIM);
    int y = rem/HWDIM;    int xx  = rem - y*HWDIM;
    band[k] = xb[c*HWDIM*HWDIM + (oy+y)*HWDIM + xx];
  }
  __syncthreads();

  float acc[OW];
#pragma unroll
  for(int i=0;i<OW;i++) acc[i]=0.f;

#pragma unroll 1
  for(int ck=0; ck<CIN*KF; ck++){
    float r[HWDIM];
    const float4* rp = (const float4*)&band[ck*HWDIM];
#pragma unroll
    for(int i=0;i<HWDIM/4;i++){
      float4 t = rp[i];
      r[4*i]=t.x; r[4*i+1]=t.y; r[4*i+2]=t.z; r[4*i+3]=t.w;
    }
    const float* wp = wT + (size_t)ck*KF*EDIM + tid;
    float wr[KF];
#pragma unroll
    for(int kx=0;kx<KF;kx++) wr[kx]=wp[kx*EDIM];
#pragma unroll
    for(int kx=0;kx<KF;kx++)
#pragma unroll
      for(int ox=0;ox<OW;ox++)
        acc[ox] += wr[kx]*r[ox+kx];
  }

  const float cb  = cbias[tid];
  const float gwe = gw[tid];
#pragma unroll 1
  for(int ox=0;ox<OW;ox++){
    float f  = acc[ox]+cb;
    float s1 = waveSum(f);
    float s2 = waveSum(f*f);
    float s3 = waveSum(f*gwe);
    if((tid&63)==0){ int wid=tid>>6; red[ox][wid*3]=s1; red[ox][wid*3+1]=s2; red[ox][wid*3+2]=s3; }
  }
  __syncthreads();
  if(tid<OW){
    float S1=red[tid][0]+red[tid][3]+red[tid][6]+red[tid][9];
    float S2=red[tid][1]+red[tid][4]+red[tid][7]+red[tid][10];
    float S3=red[tid][2]+red[tid][5]+red[tid][8]+red[tid][11];
    float mu  = S1*(1.f/EDIM);
    float var = S2*(1.f/EDIM) - mu*mu;
    float rs  = rsqrtf(var + EPSV);
    float sc  = (rs*(S3 - mu*cst[0]) + cst[1]) * (1.f/16.f);
    scores[(size_t)b*LPOS + oy*OW + tid] = sc;
  }
}

// ---------------------------------------------------------------------------
// k_topk: per-batch exact top-4 threshold (tie-safe: select all s >= kth),
// softmax weights over selected.
// ---------------------------------------------------------------------------
__global__ __launch_bounds__(256) void k_topk(const float* __restrict__ scores,
    int* __restrict__ selIdx, float* __restrict__ selW,
    int* __restrict__ nsel, float* __restrict__ denomA){
  int b=blockIdx.x, tid=threadIdx.x;
  const float* s = scores + (size_t)b*LPOS;
  float t0=-1e30f,t1=-1e30f,t2=-1e30f,t3=-1e30f;
  for(int i=tid;i<LPOS;i+=256){
    float v=s[i];
    if(v>t3){
      if(v>t0){t3=t2;t2=t1;t1=t0;t0=v;}
      else if(v>t1){t3=t2;t2=t1;t1=v;}
      else if(v>t2){t3=t2;t2=v;}
      else t3=v;
    }
  }
  __shared__ float cand[1024];
  __shared__ float sk[2];
  __shared__ int cnt;
  cand[tid*4]=t0; cand[tid*4+1]=t1; cand[tid*4+2]=t2; cand[tid*4+3]=t3;
  __syncthreads();
  if(tid==0){
    float u0=-1e30f,u1=-1e30f,u2=-1e30f,u3=-1e30f;
    for(int i=0;i<1024;i++){
      float v=cand[i];
      if(v>u3){
        if(v>u0){u3=u2;u2=u1;u1=u0;u0=v;}
        else if(v>u1){u3=u2;u2=u1;u1=v;}
        else if(v>u2){u3=u2;u2=v;}
        else u3=v;
      }
    }
    sk[0]=u0; sk[1]=u3; cnt=0;
  }
  __syncthreads();
  float smax=sk[0], kth=sk[1];
  float part=0.f;
  for(int i=tid;i<LPOS;i+=256){
    float v=s[i];
    if(v>=kth){
      float ev=expf(v-smax);
      part+=ev;
      int p=atomicAdd(&cnt,1);
      if(p<64){ selIdx[b*64+p]=i; selW[b*64+p]=ev; }
    }
  }
  part=waveSum(part);
  __shared__ float pb[4];
  if((tid&63)==0) pb[tid>>6]=part;
  __syncthreads();
  if(tid==0){ denomA[b]=pb[0]+pb[1]+pb[2]+pb[3]; nsel[b]=cnt<64?cnt:64; }
}

// ---------------------------------------------------------------------------
// k_out: per batch, recompute fields at selected positions, v-matvec,
// attn-weighted sum, LN2, relu, write (128,512) output.
// ---------------------------------------------------------------------------
__global__ __launch_bounds__(256) void k_out(const float* __restrict__ xc,
    const float* __restrict__ xt, const float* __restrict__ wT,
    const float* __restrict__ cbias, const float* __restrict__ g1,
    const float* __restrict__ b1, const float* __restrict__ wv,
    const float* __restrict__ bv, const float* __restrict__ g2,
    const float* __restrict__ b2, const int* __restrict__ selIdx,
    const float* __restrict__ selW, const int* __restrict__ nselA,
    const float* __restrict__ denomA, float* __restrict__ out){
  int b=blockIdx.x, tid=threadIdx.x;
  const float* xb = (b<128)? (xc+(size_t)b*CIN*HWDIM*HWDIM)
                           : (xt+(size_t)(b-128)*CIN*HWDIM*HWDIM);
  __shared__ float patch[2048];
  __shared__ float fld[EDIM];
  __shared__ float rbuf[8];
  int   ns   = nselA[b];
  float dinv = 1.f/denomA[b];
  float accO = 0.f;
  for(int sI=0;sI<ns;sI++){
    int   l   = selIdx[b*64+sI];
    float wgt = selW[b*64+sI]*dinv;
    int oy=l/OW, ox=l-oy*OW;
    {
      int c=tid>>3, ky=tid&7;
      const float* src = xb + c*HWDIM*HWDIM + (oy+ky)*HWDIM + ox;
#pragma unroll
      for(int kx=0;kx<KF;kx++) patch[tid*8+kx]=src[kx];
    }
    __syncthreads();
    float f=cbias[tid];
    for(int j=0;j<2048;j++) f += patch[j]*wT[(size_t)j*EDIM+tid];
    float s1=waveSum(f), s2=waveSum(f*f);
    if((tid&63)==0){ rbuf[(tid>>6)*2]=s1; rbuf[(tid>>6)*2+1]=s2; }
    __syncthreads();
    float S1=rbuf[0]+rbuf[2]+rbuf[4]+rbuf[6];
    float S2=rbuf[1]+rbuf[3]+rbuf[5]+rbuf[7];
    float mu=S1*(1.f/EDIM);
    float rs=rsqrtf(S2*(1.f/EDIM)-mu*mu+EPSV);
    fld[tid]=(f-mu)*rs*g1[tid]+b1[tid];
    __syncthreads();
    float v=bv[tid];
    const float* wr = wv + (size_t)tid*EDIM;
    for(int e2=0;e2<EDIM;e2++) v += fld[e2]*wr[e2];
    accO += wgt*v;
    __syncthreads();
  }
  float s1=waveSum(accO), s2=waveSum(accO*accO);
  if((tid&63)==0){ rbuf[(tid>>6)*2]=s1; rbuf[(tid>>6)*2+1]=s2; }
  __syncthreads();
  float S1=rbuf[0]+rbuf[2]+rbuf[4]+rbuf[6];
  float S2=rbuf[1]+rbuf[3]+rbuf[5]+rbuf[7];
  float mu=S1*(1.f/EDIM);
  float rs=rsqrtf(S2*(1.f/EDIM)-mu*mu+EPSV);
  float o=(accO-mu)*rs*g2[tid]+b2[tid];
  o = o>0.f ? o : 0.f;
  int off = (b<128)? (b*512+tid) : ((b-128)*512+256+tid);
  out[off]=o;
}

// ---------------------------------------------------------------------------
extern "C" void kernel_launch(void* const* d_in, const int* in_sizes, int n_in,
                              void* d_out, int out_size, void* d_ws, size_t ws_size,
                              hipStream_t stream){
  const float* xc = (const float*)d_in[0];
  const float* xt = (const float*)d_in[1];
  const float* cw = (const float*)d_in[2];
  const float* cb = (const float*)d_in[3];
  const float* g1 = (const float*)d_in[4];
  const float* b1 = (const float*)d_in[5];
  /* d_in[6] = wq — unused: q == bq exactly */
  const float* bq = (const float*)d_in[7];
  const float* wk = (const float*)d_in[8];
  const float* bk = (const float*)d_in[9];
  const float* wv = (const float*)d_in[10];
  const float* bv = (const float*)d_in[11];
  const float* g2 = (const float*)d_in[12];
  const float* b2 = (const float*)d_in[13];
  float* out = (float*)d_out;

  float* ws     = (float*)d_ws;
  float* wT     = ws;                      // 524288
  float* gw     = wT + 524288;             // 256
  float* cst    = gw + 256;                // 16
  float* scores = cst + 16;                // 430336
  int*   selIdx = (int*)(scores + 430336); // 256*64 ints
  float* selW   = (float*)(selIdx + 256*64);
  int*   nsel   = (int*)(selW + 256*64);
  float* denomA = (float*)(nsel + 256);

  k_prep<<<1,256,0,stream>>>(wk,bq,bk,g1,b1,gw,cst);
  k_wt<<<2048,256,0,stream>>>(cw,wT);
  dim3 g(OW, NB);
  k_conv<<<g,256,0,stream>>>(xc,xt,wT,cb,gw,cst,scores);
  k_topk<<<NB,256,0,stream>>>(scores,selIdx,selW,nsel,denomA);
  k_out<<<NB,256,0,stream>>>(xc,xt,wT,cb,g1,b1,wv,bv,g2,b2,selIdx,selW,nsel,denomA,out);
}